// Round 8
// baseline (477.128 us; speedup 1.0000x reference)
//
#include <hip/hip_runtime.h>
#include <hip/hip_bf16.h>

// GIN 3-layer + mean-pool + MLP head for MI355X (gfx950).
//
// Round-8: layers are near the ~12G random-row-fetch/s past-L2 ceiling for
// the gather itself; remaining levers are VALU (epilogue) + build scans.
//  - L1 (FO=32) epilogue split: half-wave computes k=0..31, other half
//    k=32..63 via ds_bpermute, combined with one shfl_xor(32). ~2x fewer ops.
//  - dual accumulator banks in gather loops (dependency-chain break).
//  - chunk_scan / bucket_sort use wave-level shfl scans (2-3 barriers).
//  - merged sums/cnts memset.

typedef float f4 __attribute__((ext_vector_type(4)));

#define NCHUNK 512
#define MAXK 1024  // K = ceil(N/128); N=100000 -> 782

__device__ __forceinline__ float elu_f(float x) {
  return x > 0.0f ? x : expm1f(x);
}

__device__ __forceinline__ float rl(float v, int q) {
  return __int_as_float(__builtin_amdgcn_readlane(__float_as_int(v), q));
}

__device__ __forceinline__ unsigned short f2bf(float f) {
  unsigned int u = __float_as_uint(f);
  u = (u + 0x7FFFu + ((u >> 16) & 1u)) >> 16;  // RNE
  return (unsigned short)u;
}

// unpack uint4 = 8 bf16 and accumulate into a[0..7]
__device__ __forceinline__ void acc_add8(float* a, const uint4 w) {
  a[0] += __uint_as_float(w.x << 16);
  a[1] += __uint_as_float(w.x & 0xffff0000u);
  a[2] += __uint_as_float(w.y << 16);
  a[3] += __uint_as_float(w.y & 0xffff0000u);
  a[4] += __uint_as_float(w.z << 16);
  a[5] += __uint_as_float(w.z & 0xffff0000u);
  a[6] += __uint_as_float(w.w << 16);
  a[7] += __uint_as_float(w.w & 0xffff0000u);
}

// ---------------- f32 -> bf16 conversion ----------------

__global__ __launch_bounds__(256) void cvt_bf16_kernel(
    const float* __restrict__ in, unsigned short* __restrict__ out, int n4) {
  typedef unsigned short us4 __attribute__((ext_vector_type(4)));
  const int stride = gridDim.x * blockDim.x;
  for (int i = blockIdx.x * blockDim.x + threadIdx.x; i < n4; i += stride) {
    const f4 v = *reinterpret_cast<const f4*>(in + (long long)i * 4);
    us4 o;
    o.x = f2bf(v.x); o.y = f2bf(v.y); o.z = f2bf(v.z); o.w = f2bf(v.w);
    *reinterpret_cast<us4*>(out + (long long)i * 4) = o;
  }
}

// ---------------- atomic-free CSR build ----------------

__global__ __launch_bounds__(256) void bucket_hist_kernel(
    const int* __restrict__ dst, int* __restrict__ bhist, int E, int K, int chunk) {
  __shared__ int h[MAXK];
  for (int k = threadIdx.x; k < K; k += 256) h[k] = 0;
  __syncthreads();
  const int base = blockIdx.x * chunk;
  const int end = min(E, base + chunk);
  for (int e = base + threadIdx.x; e < end; e += 256)
    atomicAdd(&h[dst[e] >> 7], 1);
  __syncthreads();
  int* row = bhist + (long long)blockIdx.x * K;
  for (int k = threadIdx.x; k < K; k += 256) row[k] = h[k];
}

// wave-shfl inclusive scan over NCHUNK=512 chunk counts for bucket k.
__global__ __launch_bounds__(NCHUNK) void chunk_scan_kernel(
    const int* __restrict__ bhist, int* __restrict__ cursors,
    int* __restrict__ btot, int K) {
  const int k = blockIdx.x;
  const int t = threadIdx.x;
  const int lane = t & 63;
  const int wv = t >> 6;  // 8 waves
  const int own = bhist[(long long)t * K + k];
  int v = own;
#pragma unroll
  for (int off = 1; off < 64; off <<= 1) {
    int u = __shfl_up(v, off, 64);
    if (lane >= off) v += u;
  }
  __shared__ int wsum[8];
  __shared__ int wpre[8];
  if (lane == 63) wsum[wv] = v;
  __syncthreads();
  if (t == 0) {
    int p = 0;
#pragma unroll
    for (int w = 0; w < 8; ++w) { wpre[w] = p; p += wsum[w]; }
  }
  __syncthreads();
  v += wpre[wv];
  cursors[(long long)t * K + k] = v - own;  // exclusive
  if (t == NCHUNK - 1) btot[k] = v;
}

__global__ __launch_bounds__(1024) void bucket_scan_kernel(
    const int* __restrict__ btot, int* __restrict__ bstart, int K) {
  __shared__ int s[1024];
  const int t = threadIdx.x;
  const int own = (t < K) ? btot[t] : 0;
  s[t] = own;
  __syncthreads();
#pragma unroll
  for (int off = 1; off < 1024; off <<= 1) {
    int v = (t >= off) ? s[t - off] : 0;
    __syncthreads();
    s[t] += v;
    __syncthreads();
  }
  if (t < K) bstart[t] = s[t] - own;
  if (t == K - 1) bstart[K] = s[t];
}

__global__ __launch_bounds__(256) void bucket_scatter_kernel(
    const int* __restrict__ src, const int* __restrict__ dst,
    const int* __restrict__ cursors, const int* __restrict__ bstart,
    int* __restrict__ packed, int E, int K, int chunk) {
  __shared__ int cur[MAXK];
  const int c = blockIdx.x;
  for (int k = threadIdx.x; k < K; k += 256)
    cur[k] = cursors[(long long)c * K + k] + bstart[k];
  __syncthreads();
  const int base = c * chunk;
  const int end = min(E, base + chunk);
  for (int e = base + threadIdx.x; e < end; e += 256) {
    const int d = dst[e];
    const int k = d >> 7;
    const int p = atomicAdd(&cur[k], 1);
    packed[p] = ((d & 127) << 18) | src[e];
  }
}

__global__ __launch_bounds__(256) void bucket_sort_kernel(
    const int* __restrict__ packed, const int* __restrict__ bstart,
    int* __restrict__ rowptr, int* __restrict__ eidx, int N, int E, int K) {
  __shared__ int hcnt[128];
  __shared__ int ccur[128];
  __shared__ int wtot;
  const int k = blockIdx.x;
  const int t = threadIdx.x;
  const int lane = t & 63;
  const int n0 = k << 7;
  const int e0 = bstart[k];
  const int e1 = bstart[k + 1];
  if (t < 128) hcnt[t] = 0;
  __syncthreads();
  for (int e = e0 + t; e < e1; e += 256)
    atomicAdd(&hcnt[packed[e] >> 18], 1);
  __syncthreads();
  int v = 0, own = 0;
  if (t < 128) {
    own = hcnt[t];
    v = own;
#pragma unroll
    for (int off = 1; off < 64; off <<= 1) {
      int u = __shfl_up(v, off, 64);
      if (lane >= off) v += u;
    }
  }
  if (t == 63) wtot = v;
  __syncthreads();
  if (t >= 64 && t < 128) v += wtot;
  if (t < 128) {
    const int excl = v - own;
    ccur[t] = excl;
    if (n0 + t < N) rowptr[n0 + t] = e0 + excl;
  }
  if (k == 0 && t == 0) rowptr[N] = E;
  __syncthreads();
  for (int e = e0 + t; e < e1; e += 256) {
    const int w = packed[e];
    const int dl = w >> 18;
    const int p = atomicAdd(&ccur[dl], 1);
    eidx[e0 + p] = w & 0x3FFFF;
  }
}

// ---------------- fused bf16 gather + MLP layers ----------------

// FI=64 bf16: 8 groups of 8 lanes; row = 128B; 8 edges/instr, unroll 2,
// dual accumulator banks. FO=32: split epilogue (half-wave per k-half via
// ds_bpermute + shfl_xor(32) combine). FO=64: readlane epilogue.
template <int FO>
__global__ __launch_bounds__(256) void gin_layer64_kernel(
    const unsigned short* __restrict__ h, const int* __restrict__ rowptr,
    const int* __restrict__ eidx, const float* __restrict__ W,
    const float* __restrict__ b, unsigned short* __restrict__ out, int N) {
  const int lane = threadIdx.x & 63;
  const int grp = lane >> 3;       // edge slot 0..7
  const int li = lane & 7;         // features li*8 .. li*8+7
  const int wid = blockIdx.x * (blockDim.x >> 6) + (threadIdx.x >> 6);
  const int nw = gridDim.x * (blockDim.x >> 6);
  const int fo = lane & (FO - 1);
  float wcol[(FO == 32) ? 32 : 64];
  if constexpr (FO == 32) {
    const int kbase = (lane >> 5) * 32;
#pragma unroll
    for (int j = 0; j < 32; ++j) wcol[j] = W[(kbase + j) * 32 + fo];
  } else {
#pragma unroll
    for (int k = 0; k < 64; ++k) wcol[k] = W[k * 64 + fo];
  }
  const float bias = b[fo];

  for (int n = wid; n < N; n += nw) {
    const int r0 = rowptr[n];
    const int cnt = rowptr[n + 1] - r0;
    float a[8] = {0.f, 0.f, 0.f, 0.f, 0.f, 0.f, 0.f, 0.f};
    float a2[8] = {0.f, 0.f, 0.f, 0.f, 0.f, 0.f, 0.f, 0.f};
    int i = grp;
    for (; i + 8 < cnt; i += 16) {
      const int s0 = eidx[r0 + i];
      const int s1 = eidx[r0 + i + 8];
      const uint4 w0 = *reinterpret_cast<const uint4*>(h + (long long)s0 * 64 + li * 8);
      const uint4 w1 = *reinterpret_cast<const uint4*>(h + (long long)s1 * 64 + li * 8);
      acc_add8(a, w0);
      acc_add8(a2, w1);
    }
    if (i < cnt) {
      const int s = eidx[r0 + i];
      acc_add8(a, *reinterpret_cast<const uint4*>(h + (long long)s * 64 + li * 8));
    }
#pragma unroll
    for (int j = 0; j < 8; ++j) {
      a[j] += a2[j];
      a[j] += __shfl_xor(a[j], 8, 64);
      a[j] += __shfl_xor(a[j], 16, 64);
      a[j] += __shfl_xor(a[j], 32, 64);
    }
    // self term (all lanes hold full agg; add own li-chunk)
    acc_add8(a, *reinterpret_cast<const uint4*>(h + (long long)n * 64 + li * 8));
    if constexpr (FO == 32) {
      // lanes <32: k=0..31 (+bias); lanes >=32: k=32..63; combine via xor(32).
      float o = (lane < 32) ? bias : 0.0f;
      const int pbase = (lane >> 5) * 16;  // bpermute byte base: src lanes 0..3 / 4..7
#pragma unroll
      for (int j = 0; j < 32; ++j) {
        const float av = __int_as_float(__builtin_amdgcn_ds_bpermute(
            pbase + (j >> 3) * 4, __float_as_int(a[j & 7])));
        o = fmaf(av, wcol[j], o);
      }
      o += __shfl_xor(o, 32, 64);
      if (lane < 32) out[(long long)n * 32 + lane] = f2bf(elu_f(o));
    } else {
      float o0 = bias, o1 = 0.0f;
#pragma unroll
      for (int k = 0; k < 64; k += 2) {
        o0 = fmaf(rl(a[k & 7], k >> 3), wcol[k], o0);
        o1 = fmaf(rl(a[(k + 1) & 7], (k + 1) >> 3), wcol[k + 1], o1);
      }
      out[(long long)n * 64 + lane] = f2bf(elu_f(o0 + o1));
    }
  }
}

// FI=32 bf16, FO=64: 16 groups of 4 lanes; row = 64B; 16 edges/instr,
// unroll 2, dual banks.
__global__ __launch_bounds__(256) void gin_layer32_kernel(
    const unsigned short* __restrict__ h, const int* __restrict__ rowptr,
    const int* __restrict__ eidx, const float* __restrict__ W,
    const float* __restrict__ b, unsigned short* __restrict__ out, int N) {
  const int lane = threadIdx.x & 63;
  const int grp = lane >> 2;       // edge slot 0..15
  const int li = lane & 3;         // features li*8 .. li*8+7
  const int wid = blockIdx.x * (blockDim.x >> 6) + (threadIdx.x >> 6);
  const int nw = gridDim.x * (blockDim.x >> 6);
  float wcol[32];
#pragma unroll
  for (int k = 0; k < 32; ++k) wcol[k] = W[k * 64 + lane];
  const float bias = b[lane];

  for (int n = wid; n < N; n += nw) {
    const int r0 = rowptr[n];
    const int cnt = rowptr[n + 1] - r0;
    float a[8] = {0.f, 0.f, 0.f, 0.f, 0.f, 0.f, 0.f, 0.f};
    float a2[8] = {0.f, 0.f, 0.f, 0.f, 0.f, 0.f, 0.f, 0.f};
    int i = grp;
    for (; i + 16 < cnt; i += 32) {
      const int s0 = eidx[r0 + i];
      const int s1 = eidx[r0 + i + 16];
      const uint4 w0 = *reinterpret_cast<const uint4*>(h + (long long)s0 * 32 + li * 8);
      const uint4 w1 = *reinterpret_cast<const uint4*>(h + (long long)s1 * 32 + li * 8);
      acc_add8(a, w0);
      acc_add8(a2, w1);
    }
    if (i < cnt) {
      const int s = eidx[r0 + i];
      acc_add8(a, *reinterpret_cast<const uint4*>(h + (long long)s * 32 + li * 8));
    }
#pragma unroll
    for (int j = 0; j < 8; ++j) {
      a[j] += a2[j];
      a[j] += __shfl_xor(a[j], 4, 64);
      a[j] += __shfl_xor(a[j], 8, 64);
      a[j] += __shfl_xor(a[j], 16, 64);
      a[j] += __shfl_xor(a[j], 32, 64);
    }
    acc_add8(a, *reinterpret_cast<const uint4*>(h + (long long)n * 32 + li * 8));
    float o0 = bias, o1 = 0.0f;
#pragma unroll
    for (int k = 0; k < 32; k += 2) {
      o0 = fmaf(rl(a[k & 7], k >> 3), wcol[k], o0);
      o1 = fmaf(rl(a[(k + 1) & 7], (k + 1) >> 3), wcol[k + 1], o1);
    }
    out[(long long)n * 64 + lane] = f2bf(elu_f(o0 + o1));
  }
}

// ---------------- pooling + head ----------------

__global__ void pool_kernel(const unsigned short* __restrict__ h,
                            const int* __restrict__ batch,
                            float* __restrict__ sums,
                            float* __restrict__ cnts,
                            int N) {
  const int groupsPerBlock = blockDim.x >> 6;
  const int grp = blockIdx.x * groupsPerBlock + (threadIdx.x >> 6);
  const int ngrp = gridDim.x * groupsPerBlock;
  const int f = threadIdx.x & 63;
  const int chunk = (N + ngrp - 1) / ngrp;
  const int n0 = grp * chunk;
  const int n1 = min(N, n0 + chunk);
  if (n0 >= n1) return;
  int g = batch[n0];
  float acc = 0.0f;
  float cnt = 0.0f;
  for (int n = n0; n < n1; ++n) {
    const int bg = batch[n];
    if (bg != g) {
      atomicAdd(&sums[(long long)g * 64 + f], acc);
      if (f == 0) atomicAdd(&cnts[g], cnt);
      acc = 0.0f;
      cnt = 0.0f;
      g = bg;
    }
    acc += __uint_as_float((unsigned int)h[(long long)n * 64 + f] << 16);
    cnt += 1.0f;
  }
  atomicAdd(&sums[(long long)g * 64 + f], acc);
  if (f == 0) atomicAdd(&cnts[g], cnt);
}

__global__ void head_kernel(const float* __restrict__ sums,
                            const float* __restrict__ cnts,
                            const float* __restrict__ Wf1, const float* __restrict__ bf1,
                            const float* __restrict__ Wf2, const float* __restrict__ bf2,
                            const float* __restrict__ Wf3, const float* __restrict__ bf3,
                            float* __restrict__ out, int G) {
  __shared__ float s0[64];
  __shared__ float s1[64];
  __shared__ float s2[32];
  const int g = blockIdx.x;
  const int t = threadIdx.x;
  const float c = fmaxf(cnts[g], 1.0f);
  s0[t] = sums[(long long)g * 64 + t] / c;
  __syncthreads();
  float acc = bf1[t];
#pragma unroll
  for (int k = 0; k < 64; ++k) acc += s0[k] * Wf1[k * 64 + t];
  s1[t] = elu_f(acc);
  __syncthreads();
  if (t < 32) {
    float a2 = bf2[t];
#pragma unroll
    for (int k = 0; k < 64; ++k) a2 += s1[k] * Wf2[k * 32 + t];
    s2[t] = elu_f(a2) * Wf3[t];
  }
  __syncthreads();
  if (t == 0) {
    float r = bf3[0];
#pragma unroll
    for (int k = 0; k < 32; ++k) r += s2[k];
    out[g] = r;
  }
}

extern "C" void kernel_launch(void* const* d_in, const int* in_sizes, int n_in,
                              void* d_out, int out_size, void* d_ws, size_t ws_size,
                              hipStream_t stream) {
  const float* x   = (const float*)d_in[0];
  const int* ei    = (const int*)d_in[1];
  const int* batch = (const int*)d_in[2];
  const float* W1  = (const float*)d_in[4];
  const float* b1  = (const float*)d_in[5];
  const float* W2  = (const float*)d_in[6];
  const float* b2  = (const float*)d_in[7];
  const float* W3  = (const float*)d_in[8];
  const float* b3  = (const float*)d_in[9];
  const float* Wf1 = (const float*)d_in[10];
  const float* bf1 = (const float*)d_in[11];
  const float* Wf2 = (const float*)d_in[12];
  const float* bf2 = (const float*)d_in[13];
  const float* Wf3 = (const float*)d_in[14];
  const float* bf3 = (const float*)d_in[15];

  const int N = in_sizes[0] / 64;
  const int E = in_sizes[1] / 2;
  const int G = out_size;
  const int* src = ei;
  const int* dst = ei + E;
  const int K = (N + 127) >> 7;
  const int chunk = (E + NCHUNK - 1) / NCHUNK;

  char* ws = (char*)d_ws;
  size_t off = 0;
  auto alloc = [&](size_t bytes) -> void* {
    void* p = ws + off;
    off = (off + bytes + 255) & ~(size_t)255;
    return p;
  };
  int* bhist   = (int*)alloc((size_t)NCHUNK * K * 4);
  int* cursors = (int*)alloc((size_t)NCHUNK * K * 4);
  int* btot    = (int*)alloc((size_t)K * 4);
  int* bstart  = (int*)alloc((size_t)(K + 1) * 4);
  int* rowptr  = (int*)alloc((size_t)(N + 1) * 4);
  int* eidx    = (int*)alloc((size_t)E * 4);
  int* packed  = (int*)alloc((size_t)E * 4);
  unsigned short* xb = (unsigned short*)alloc((size_t)N * 64 * 2);
  unsigned short* hA = (unsigned short*)alloc((size_t)N * 64 * 2);
  unsigned short* hB = (unsigned short*)alloc((size_t)N * 64 * 2);
  float* sums  = (float*)alloc((size_t)G * 65 * 4);  // sums[G*64] + cnts[G]
  float* cnts  = sums + (size_t)G * 64;
  float* out   = (float*)d_out;

  // ---- x -> bf16 ----
  cvt_bf16_kernel<<<1024, 256, 0, stream>>>(x, xb, N * 16);

  // ---- atomic-free CSR build ----
  bucket_hist_kernel<<<NCHUNK, 256, 0, stream>>>(dst, bhist, E, K, chunk);
  chunk_scan_kernel<<<K, NCHUNK, 0, stream>>>(bhist, cursors, btot, K);
  bucket_scan_kernel<<<1, 1024, 0, stream>>>(btot, bstart, K);
  bucket_scatter_kernel<<<NCHUNK, 256, 0, stream>>>(src, dst, cursors, bstart,
                                                    packed, E, K, chunk);
  bucket_sort_kernel<<<K, 256, 0, stream>>>(packed, bstart, rowptr, eidx, N, E, K);

  // ---- layers (bf16 features) ----
  gin_layer64_kernel<32><<<2048, 256, 0, stream>>>(xb, rowptr, eidx, W1, b1, hA, N);
  gin_layer32_kernel<<<2048, 256, 0, stream>>>(hA, rowptr, eidx, W2, b2, hB, N);
  gin_layer64_kernel<64><<<2048, 256, 0, stream>>>(hB, rowptr, eidx, W3, b3, hA, N);

  // ---- mean pool + head ----
  hipMemsetAsync(sums, 0, (size_t)G * 65 * 4, stream);
  pool_kernel<<<512, 256, 0, stream>>>(hA, batch, sums, cnts, N);
  head_kernel<<<G, 64, 0, stream>>>(sums, cnts, Wf1, bf1, Wf2, bf2, Wf3, bf3, out, G);
}